// Round 2
// baseline (673.002 us; speedup 1.0000x reference)
//
#include <hip/hip_runtime.h>
#include <hip/hip_bf16.h>
#include <math.h>

typedef __bf16 bf16;
typedef __attribute__((ext_vector_type(8))) __bf16 bf16x8;
typedef __attribute__((ext_vector_type(4))) float f32x4;

typedef const uint32_t __attribute__((address_space(1)))* gp1_t;
typedef uint32_t __attribute__((address_space(3)))* lp3_t;

__device__ __forceinline__ void async_load16(const void* g, void* l) {
    // global -> LDS direct, 16B per lane; LDS dest = wave-uniform base + lane*16
    __builtin_amdgcn_global_load_lds((gp1_t)g, (lp3_t)l, 16, 0, 0);
}

__device__ __forceinline__ float softplus_f(float x) {
    // numerically stable softplus; rho ~ -3 so exp path is well-conditioned
    return fmaxf(x, 0.0f) + log1pf(__expf(-fabsf(x)));
}

#define IN_F  4096
#define OUT_F 4096
#define BATCH 8192

#define BM 128
#define BN 128
#define BK 32

// ---- Kernel 0: x fp32 -> bf16 (for MFMA staging) ----
__global__ __launch_bounds__(256) void convert_x(
    const float* __restrict__ x, bf16* __restrict__ xb)
{
    const int i = (blockIdx.x * 256 + threadIdx.x) * 8;
    float4 a = *(const float4*)(x + i);
    float4 b = *(const float4*)(x + i + 4);
    bf16x8 o;
    o[0] = (bf16)a.x; o[1] = (bf16)a.y; o[2] = (bf16)a.z; o[3] = (bf16)a.w;
    o[4] = (bf16)b.x; o[5] = (bf16)b.y; o[6] = (bf16)b.z; o[7] = (bf16)b.w;
    *(bf16x8*)(xb + i) = o;
}

// ---- Kernel 1: W[o,i] = mu + softplus(rho) * eps  (fp32 in, bf16 out) ----
__global__ __launch_bounds__(256) void make_weight(
    const float* __restrict__ mu, const float* __restrict__ rho,
    const float* __restrict__ eps, bf16* __restrict__ W)
{
    const int i = (blockIdx.x * 256 + threadIdx.x) * 8;
    bf16x8 w;
#pragma unroll
    for (int h = 0; h < 2; ++h) {
        float4 m = *(const float4*)(mu + i + h * 4);
        float4 r = *(const float4*)(rho + i + h * 4);
        float4 e = *(const float4*)(eps + i + h * 4);
        w[h * 4 + 0] = (bf16)(m.x + softplus_f(r.x) * e.x);
        w[h * 4 + 1] = (bf16)(m.y + softplus_f(r.y) * e.y);
        w[h * 4 + 2] = (bf16)(m.z + softplus_f(r.z) * e.z);
        w[h * 4 + 3] = (bf16)(m.w + softplus_f(r.w) * e.w);
    }
    *(bf16x8*)(W + i) = w;
}

// ---- Kernel 2: C[M,N] = A[M,K] * W[N,K]^T + bias  (m97-style 128x128x32) ----
__global__ __launch_bounds__(256) void gemm_bt_bias(
    const bf16* __restrict__ A,    // x in bf16 [M,K]
    const bf16* __restrict__ W,    // sampled weight bf16 [N,K]
    const float* __restrict__ bmu, const float* __restrict__ brho,
    const float* __restrict__ beps,
    float* __restrict__ C)         // [M,N] fp32
{
    const int K = IN_F;
    const int N = OUT_F;

    __shared__ __align__(16) bf16 As[BM * BK];  // 8 KB, row-major [128][32]
    __shared__ __align__(16) bf16 Bs[BN * BK];  // 8 KB, row-major [128][32]

    const int tid  = threadIdx.x;
    const int wave = tid >> 6;
    const int lane = tid & 63;

    const int bn = blockIdx.x & 31;   // N/BN = 32
    const int bm = blockIdx.x >> 5;
    const int row0 = bm * BM;
    const int col0 = bn * BN;

    // 2x2 waves, each computes a 64x64 sub-tile as 4x4 MFMA tiles of 16x16
    const int wm   = (wave >> 1) * 64;
    const int wn   = (wave & 1) * 64;
    const int l15  = lane & 15;
    const int quad = lane >> 4;

    const f32x4 zero = {0.f, 0.f, 0.f, 0.f};
    f32x4 acc[4][4];
#pragma unroll
    for (int i = 0; i < 4; ++i)
#pragma unroll
        for (int j = 0; j < 4; ++j) acc[i][j] = zero;

    // Staging: thread tid covers LDS bytes [tid*16, tid*16+16) of each half-tile
    // == tile row tid>>2, k-chunk (tid&3)*8 elements.
    const int srow = tid >> 2;
    const int scol = (tid & 3) << 3;
    const bf16* gA0 = A + (size_t)(row0 + srow) * K + scol;
    const bf16* gA1 = gA0 + (size_t)64 * K;
    const bf16* gB0 = W + (size_t)(col0 + srow) * K + scol;
    const bf16* gB1 = gB0 + (size_t)64 * K;

    char* ldsA0 = (char*)As + wave * 1024;
    char* ldsA1 = (char*)As + 4096 + wave * 1024;
    char* ldsB0 = (char*)Bs + wave * 1024;
    char* ldsB1 = (char*)Bs + 4096 + wave * 1024;

    for (int k0 = 0; k0 < K; k0 += BK) {
        async_load16(gA0 + k0, ldsA0);
        async_load16(gA1 + k0, ldsA1);
        async_load16(gB0 + k0, ldsB0);
        async_load16(gB1 + k0, ldsB1);
        __syncthreads();  // vmcnt drain + barrier: tiles visible to all waves

        bf16x8 a[4], b[4];
#pragma unroll
        for (int mt = 0; mt < 4; ++mt)
            a[mt] = *(const bf16x8*)&As[(wm + mt * 16 + l15) * BK + quad * 8];
#pragma unroll
        for (int nt = 0; nt < 4; ++nt)
            b[nt] = *(const bf16x8*)&Bs[(wn + nt * 16 + l15) * BK + quad * 8];

#pragma unroll
        for (int mt = 0; mt < 4; ++mt)
#pragma unroll
            for (int nt = 0; nt < 4; ++nt)
                acc[mt][nt] = __builtin_amdgcn_mfma_f32_16x16x32_bf16(
                    a[mt], b[nt], acc[mt][nt], 0, 0, 0);

        __syncthreads();  // all waves done reading before next overwrite
    }

    // Epilogue: bias = bmu + softplus(brho)*beps per output column, fused (fp32)
    float bias[4];
#pragma unroll
    for (int nt = 0; nt < 4; ++nt) {
        const int col = col0 + wn + nt * 16 + l15;
        bias[nt] = bmu[col] + softplus_f(brho[col]) * beps[col];
    }

    // C/D layout (16x16x32): col = lane&15, row = (lane>>4)*4 + reg
#pragma unroll
    for (int mt = 0; mt < 4; ++mt) {
#pragma unroll
        for (int r = 0; r < 4; ++r) {
            const size_t row = row0 + wm + mt * 16 + quad * 4 + r;
#pragma unroll
            for (int nt = 0; nt < 4; ++nt) {
                const int col = col0 + wn + nt * 16 + l15;
                C[row * N + col] = acc[mt][nt][r] + bias[nt];
            }
        }
    }
}

extern "C" void kernel_launch(void* const* d_in, const int* in_sizes, int n_in,
                              void* d_out, int out_size, void* d_ws, size_t ws_size,
                              hipStream_t stream) {
    const float* x    = (const float*)d_in[0];  // [BATCH, IN_F]
    const float* wmu  = (const float*)d_in[1];  // [OUT_F, IN_F]
    const float* wrho = (const float*)d_in[2];  // [OUT_F, IN_F]
    const float* bmu  = (const float*)d_in[3];  // [OUT_F]
    const float* brho = (const float*)d_in[4];  // [OUT_F]
    const float* weps = (const float*)d_in[5];  // [OUT_F, IN_F]
    const float* beps = (const float*)d_in[6];  // [OUT_F]
    float* out = (float*)d_out;                 // [BATCH, OUT_F] fp32

    // Workspace layout: [0, 64MB) xb bf16; [64MB, 96MB) W bf16
    bf16* xb = (bf16*)d_ws;
    bf16* W  = (bf16*)((char*)d_ws + (size_t)BATCH * IN_F * sizeof(bf16));

    // Kernel 0: convert x to bf16 (33.5M elems, 8/thread)
    convert_x<<<(BATCH * IN_F) / (256 * 8), 256, 0, stream>>>(x, xb);

    // Kernel 1: materialize sampled weight in bf16 (16.78M elems, 8/thread)
    make_weight<<<(OUT_F * IN_F) / (256 * 8), 256, 0, stream>>>(wmu, wrho, weps, W);

    // Kernel 2: GEMM + fused bias epilogue, fp32 output
    gemm_bt_bias<<<(BATCH / BM) * (OUT_F / BN), 256, 0, stream>>>(
        xb, W, bmu, brho, beps, out);
}

// Round 3
// 643.420 us; speedup vs baseline: 1.0460x; 1.0460x over previous
//
#include <hip/hip_runtime.h>
#include <hip/hip_bf16.h>
#include <math.h>

typedef __bf16 bf16;
typedef __attribute__((ext_vector_type(8))) __bf16 bf16x8;
typedef __attribute__((ext_vector_type(4))) float f32x4;

typedef const uint32_t __attribute__((address_space(1)))* gp1_t;
typedef uint32_t __attribute__((address_space(3)))* lp3_t;

__device__ __forceinline__ void async_load16(const void* g, void* l) {
    // global -> LDS direct, 16B per lane; LDS dest = wave-uniform base + lane*16
    __builtin_amdgcn_global_load_lds((gp1_t)g, (lp3_t)l, 16, 0, 0);
}

__device__ __forceinline__ float softplus_f(float x) {
    return fmaxf(x, 0.0f) + log1pf(__expf(-fabsf(x)));
}

#define IN_F  4096
#define OUT_F 4096
#define BATCH 8192

#define BM 128
#define BN 128

// blocks for the two prologue regions
#define NXB ((BATCH * IN_F) / (256 * 8))   // 16384: x fp32->bf16
#define NWB ((OUT_F * IN_F) / (256 * 8))   //  8192: W = mu + softplus(rho)*eps

// ---- Fused prologue: region 0 converts x, region 1 samples W ----
__global__ __launch_bounds__(256) void prologue(
    const float* __restrict__ x,
    const float* __restrict__ mu, const float* __restrict__ rho,
    const float* __restrict__ eps,
    bf16* __restrict__ xb, bf16* __restrict__ W)
{
    const int b = blockIdx.x;
    if (b < NXB) {
        const int i = (b * 256 + threadIdx.x) * 8;
        float4 a = *(const float4*)(x + i);
        float4 c = *(const float4*)(x + i + 4);
        bf16x8 o;
        o[0] = (bf16)a.x; o[1] = (bf16)a.y; o[2] = (bf16)a.z; o[3] = (bf16)a.w;
        o[4] = (bf16)c.x; o[5] = (bf16)c.y; o[6] = (bf16)c.z; o[7] = (bf16)c.w;
        *(bf16x8*)(xb + i) = o;
    } else {
        const int i = ((b - NXB) * 256 + threadIdx.x) * 8;
        bf16x8 w;
#pragma unroll
        for (int h = 0; h < 2; ++h) {
            float4 m = *(const float4*)(mu + i + h * 4);
            float4 r = *(const float4*)(rho + i + h * 4);
            float4 e = *(const float4*)(eps + i + h * 4);
            w[h * 4 + 0] = (bf16)(m.x + softplus_f(r.x) * e.x);
            w[h * 4 + 1] = (bf16)(m.y + softplus_f(r.y) * e.y);
            w[h * 4 + 2] = (bf16)(m.z + softplus_f(r.z) * e.z);
            w[h * 4 + 3] = (bf16)(m.w + softplus_f(r.w) * e.w);
        }
        *(bf16x8*)(W + i) = w;
    }
}

// ---- GEMM: C[M,N] = A[M,K] * W[N,K]^T + bias, BK=64 (2x 32-deep halves) ----
// BK=64 halves the barrier count vs m97's BK=32: one vmcnt drain now covers
// 32 MFMAs instead of 16. LDS layout = two concatenated BK=32 tiles so the
// global_load_lds chunk order (wave-uniform base + lane*16) is unchanged.
__global__ __launch_bounds__(256, 3) void gemm_bt_bias(
    const bf16* __restrict__ A,    // x bf16 [M,K]
    const bf16* __restrict__ W,    // sampled weight bf16 [N,K]
    const float* __restrict__ bmu, const float* __restrict__ brho,
    const float* __restrict__ beps,
    float* __restrict__ C)         // [M,N] fp32
{
    const int K = IN_F;
    const int N = OUT_F;

    __shared__ __align__(16) bf16 As[2][BM * 32];  // 16 KB: k-halves of BK=64
    __shared__ __align__(16) bf16 Bs[2][BN * 32];  // 16 KB

    const int tid  = threadIdx.x;
    const int wave = tid >> 6;
    const int lane = tid & 63;

    const int bn = blockIdx.x & 31;   // N/BN = 32
    const int bm = blockIdx.x >> 5;
    const int row0 = bm * BM;
    const int col0 = bn * BN;

    const int wm   = (wave >> 1) * 64;
    const int wn   = (wave & 1) * 64;
    const int l15  = lane & 15;
    const int quad = lane >> 4;

    const f32x4 zero = {0.f, 0.f, 0.f, 0.f};
    f32x4 acc[4][4];
#pragma unroll
    for (int i = 0; i < 4; ++i)
#pragma unroll
        for (int j = 0; j < 4; ++j) acc[i][j] = zero;

    // Staging: thread tid covers LDS bytes [tid*16, +16) of each 64-row half:
    // row = tid>>2, k-chunk = (tid&3)*8 elements.
    const int srow = tid >> 2;
    const int scol = (tid & 3) << 3;
    const bf16* gA0 = A + (size_t)(row0 + srow) * K + scol;
    const bf16* gA1 = gA0 + (size_t)64 * K;
    const bf16* gB0 = W + (size_t)(col0 + srow) * K + scol;
    const bf16* gB1 = gB0 + (size_t)64 * K;

    char* const ldsA = (char*)As + wave * 1024;
    char* const ldsB = (char*)Bs + wave * 1024;

    for (int k0 = 0; k0 < K; k0 += 64) {
        // 8 async issues, one drain for all of them at the barrier
        async_load16(gA0 + k0,      ldsA);
        async_load16(gA1 + k0,      ldsA + 4096);
        async_load16(gA0 + k0 + 32, ldsA + 8192);
        async_load16(gA1 + k0 + 32, ldsA + 12288);
        async_load16(gB0 + k0,      ldsB);
        async_load16(gB1 + k0,      ldsB + 4096);
        async_load16(gB0 + k0 + 32, ldsB + 8192);
        async_load16(gB1 + k0 + 32, ldsB + 12288);
        __syncthreads();

#pragma unroll
        for (int h = 0; h < 2; ++h) {
            bf16x8 a[4], b[4];
#pragma unroll
            for (int mt = 0; mt < 4; ++mt)
                a[mt] = *(const bf16x8*)&As[h][(wm + mt * 16 + l15) * 32 + quad * 8];
#pragma unroll
            for (int nt = 0; nt < 4; ++nt)
                b[nt] = *(const bf16x8*)&Bs[h][(wn + nt * 16 + l15) * 32 + quad * 8];

#pragma unroll
            for (int mt = 0; mt < 4; ++mt)
#pragma unroll
                for (int nt = 0; nt < 4; ++nt)
                    acc[mt][nt] = __builtin_amdgcn_mfma_f32_16x16x32_bf16(
                        a[mt], b[nt], acc[mt][nt], 0, 0, 0);
        }

        __syncthreads();
    }

    // Epilogue: bias = bmu + softplus(brho)*beps, fused (fp32)
    float bias[4];
#pragma unroll
    for (int nt = 0; nt < 4; ++nt) {
        const int col = col0 + wn + nt * 16 + l15;
        bias[nt] = bmu[col] + softplus_f(brho[col]) * beps[col];
    }

    // C/D layout (16x16x32): col = lane&15, row = (lane>>4)*4 + reg
#pragma unroll
    for (int mt = 0; mt < 4; ++mt) {
#pragma unroll
        for (int r = 0; r < 4; ++r) {
            const size_t row = row0 + wm + mt * 16 + quad * 4 + r;
#pragma unroll
            for (int nt = 0; nt < 4; ++nt) {
                const int col = col0 + wn + nt * 16 + l15;
                C[row * N + col] = acc[mt][nt][r] + bias[nt];
            }
        }
    }
}

extern "C" void kernel_launch(void* const* d_in, const int* in_sizes, int n_in,
                              void* d_out, int out_size, void* d_ws, size_t ws_size,
                              hipStream_t stream) {
    const float* x    = (const float*)d_in[0];
    const float* wmu  = (const float*)d_in[1];
    const float* wrho = (const float*)d_in[2];
    const float* bmu  = (const float*)d_in[3];
    const float* brho = (const float*)d_in[4];
    const float* weps = (const float*)d_in[5];
    const float* beps = (const float*)d_in[6];
    float* out = (float*)d_out;

    bf16* xb = (bf16*)d_ws;
    bf16* W  = (bf16*)((char*)d_ws + (size_t)BATCH * IN_F * sizeof(bf16));

    prologue<<<NXB + NWB, 256, 0, stream>>>(x, wmu, wrho, weps, xb, W);

    gemm_bt_bias<<<(BATCH / BM) * (OUT_F / BN), 256, 0, stream>>>(
        xb, W, bmu, brho, beps, out);
}